// Round 6
// baseline (215.171 us; speedup 1.0000x reference)
//
#include <hip/hip_runtime.h>

#define HID 1024
#define SEQ 2048
#define NB 2
#define NH 16
#define HD 64

// 0.125 * log2(e)  (1/sqrt(64) folded into log2 domain)
#define C1 0.1803368801111204f
// gamma * log2(e)
#define C2 0.7213475204444817f

typedef __attribute__((ext_vector_type(8))) short bf16x8;
typedef __attribute__((ext_vector_type(8))) unsigned short u16x8;
typedef __attribute__((ext_vector_type(4))) float f32x4;

__device__ __forceinline__ unsigned short f2bf(float f) {
  unsigned u = __builtin_bit_cast(unsigned, f);
  u += 0x7fffu + ((u >> 16) & 1u);
  return (unsigned short)(u >> 16);
}
__device__ __forceinline__ float bf2f(unsigned short u) {
  return __builtin_bit_cast(float, ((unsigned)u) << 16);
}

#define GLOAD16(gsrc, ldst)                                                     \
  __builtin_amdgcn_global_load_lds(                                             \
      (const __attribute__((address_space(1))) void*)(gsrc),                    \
      (__attribute__((address_space(3))) void*)(ldst), 16, 0, 0)

// ---- convert the 4 weight matrices f32 -> bf16 into one contiguous buffer ----
__global__ __launch_bounds__(256) void convert_w_kernel(
    const float* __restrict__ Wq, const float* __restrict__ Wk,
    const float* __restrict__ Wv, const float* __restrict__ Wo,
    unsigned short* __restrict__ Wb) {
  int i = blockIdx.x * 256 + threadIdx.x;
  const int per = (HID * HID) / 8;
  int m = i / per;
  const float* sp = (m == 0) ? Wq : (m == 1) ? Wk : (m == 2) ? Wv : Wo;
  int j = (i - m * per) * 8;
  const float4* p = reinterpret_cast<const float4*>(sp + j);
  float4 a = p[0], b = p[1];
  u16x8 o;
  o[0] = f2bf(a.x); o[1] = f2bf(a.y); o[2] = f2bf(a.z); o[3] = f2bf(a.w);
  o[4] = f2bf(b.x); o[5] = f2bf(b.y); o[6] = f2bf(b.z); o[7] = f2bf(b.w);
  *reinterpret_cast<u16x8*>(Wb + (size_t)i * 8) = o;
}

// ---- per-row L2 norm of x; emit x (bf16) and normalized x (bf16) ----
__global__ __launch_bounds__(256) void rownorm_kernel(
    const float* __restrict__ x, unsigned short* __restrict__ xb,
    unsigned short* __restrict__ nxb) {
  int row = blockIdx.x, tid = threadIdx.x;
  const float4 v = reinterpret_cast<const float4*>(x + (size_t)row * HID)[tid];
  float ss = v.x * v.x + v.y * v.y + v.z * v.z + v.w * v.w;
#pragma unroll
  for (int off = 32; off; off >>= 1) ss += __shfl_xor(ss, off, 64);
  __shared__ float wsum[4];
  if ((tid & 63) == 0) wsum[tid >> 6] = ss;
  __syncthreads();
  float tot = wsum[0] + wsum[1] + wsum[2] + wsum[3];
  float inv = 1.0f / fmaxf(sqrtf(tot), 1e-12f);
  ushort4 a, b;
  a.x = f2bf(v.x); a.y = f2bf(v.y); a.z = f2bf(v.z); a.w = f2bf(v.w);
  b.x = f2bf(v.x * inv); b.y = f2bf(v.y * inv);
  b.z = f2bf(v.z * inv); b.w = f2bf(v.w * inv);
  reinterpret_cast<ushort4*>(xb  + (size_t)row * HID)[tid] = a;
  reinterpret_cast<ushort4*>(nxb + (size_t)row * HID)[tid] = b;
}

// ---- generic NT bf16 GEMM: C = A[M,K] * B[N,K]^T, f32 accum ----
// Staging via global_load_lds width=16 into unpadded [128][32] tiles.
template <int MODE>
__global__ __launch_bounds__(256) void gemm_nt(
    const unsigned short* __restrict__ A, long strideA,
    const unsigned short* __restrict__ B, long strideB,
    void* __restrict__ Cv, long strideC, int ldc,
    int M, int N, int K,
    const float* __restrict__ b0, const float* __restrict__ b1,
    const float* __restrict__ b2, const unsigned char* __restrict__ mask) {
  __shared__ __align__(16) unsigned short As[128 * 32];
  __shared__ __align__(16) unsigned short Bs[128 * 32];
  int tid = threadIdx.x, lane = tid & 63, wid = tid >> 6;
  int g = lane >> 4, lr = lane & 15;
  int wr = wid >> 1, wc = wid & 1;
  int m0 = blockIdx.y * 128, n0 = blockIdx.x * 128;
  const unsigned short* Ab = A + (size_t)blockIdx.z * strideA
      + (size_t)(m0 + wid * 32 + (lane >> 2)) * K + (lane & 3) * 8;
  const unsigned short* Bb = B + (size_t)blockIdx.z * strideB
      + (size_t)(n0 + wid * 32 + (lane >> 2)) * K + (lane & 3) * 8;
  unsigned short* la = As + wid * 1024;
  unsigned short* lb = Bs + wid * 1024;
  f32x4 acc[4][4] = {};
  for (int k0 = 0; k0 < K; k0 += 32) {
    GLOAD16(Ab + k0, la);
    GLOAD16(Ab + 16 * K + k0, la + 512);
    GLOAD16(Bb + k0, lb);
    GLOAD16(Bb + 16 * K + k0, lb + 512);
    __syncthreads();
    bf16x8 af[4], bfr[4];
#pragma unroll
    for (int i = 0; i < 4; i++) {
      af[i]  = *reinterpret_cast<const bf16x8*>(&As[(wr * 64 + i * 16 + lr) * 32 + g * 8]);
      bfr[i] = *reinterpret_cast<const bf16x8*>(&Bs[(wc * 64 + i * 16 + lr) * 32 + g * 8]);
    }
#pragma unroll
    for (int i = 0; i < 4; i++)
#pragma unroll
      for (int j = 0; j < 4; j++)
        acc[i][j] = __builtin_amdgcn_mfma_f32_16x16x32_bf16(af[i], bfr[j], acc[i][j], 0, 0, 0);
    __syncthreads();
  }
#pragma unroll
  for (int i = 0; i < 4; i++)
#pragma unroll
    for (int j = 0; j < 4; j++) {
      int col = n0 + wc * 64 + j * 16 + lr;
#pragma unroll
      for (int r = 0; r < 4; r++) {
        int row = m0 + wr * 64 + i * 16 + 4 * g + r;
        float v = acc[i][j][r];
        if (MODE == 0) {
          const float* bp = (col < 1024) ? b0 : (col < 2048 ? b1 : b2);
          v += bp[col & 1023];
          ((unsigned short*)Cv)[(size_t)blockIdx.z * strideC + (size_t)row * ldc + col] = f2bf(v);
        } else if (MODE == 1) {
          float t = -C2 * v + (mask[(size_t)row * N + col] ? -1e30f : 0.0f);
          ((unsigned short*)Cv)[(size_t)blockIdx.z * strideC + (size_t)row * ldc + col] = f2bf(t);
        } else {
          v += b0[col];
          ((float*)Cv)[(size_t)blockIdx.z * strideC + (size_t)row * ldc + col] = v;
        }
      }
    }
}

// ---- flash attention v5: no-max softmax (log2 domain), 4 waves x 16 q-rows ----
// lane (g,lr) holds S^T[key=kc*16+4g+r][q=lr]; P = exp2(s) directly (score max
// ~9 << 128 overflow; row-uniform exponent cancels in num/den ratio exactly).
__global__ __launch_bounds__(256, 4) void flash_kernel(
    const unsigned short* __restrict__ QKV,  // [4096][3072] bf16 (Q|K|V)
    const unsigned short* __restrict__ D2,   // [2][2048][2048] bf16 log2-bias
    unsigned short* __restrict__ ctxb) {     // [4096][1024] bf16
  int h = blockIdx.x, qt = blockIdx.y, b = blockIdx.z;
  int tid = threadIdx.x, wid = tid >> 6, lane = tid & 63;
  int g = lane >> 4, lr = lane & 15;
  __shared__ __align__(16) unsigned short Ks[2][64 * 64];  // 16 KiB
  __shared__ __align__(16) unsigned short Vt[2][64 * 64];  // 16 KiB
  __shared__ __align__(16) unsigned short Pl[4][16 * 64];  // 8 KiB (XOR-swizzled)
  const size_t ld = 3 * HID;
  const size_t bS = (size_t)b * SEQ;
  const int qbase = qt * 64 + wid * 16;

  // Q fragment (B operand): rows qbase+lr; lane group g holds d=8g+j (+32)
  const unsigned short* qp = QKV + (bS + qbase + lr) * ld + h * HD + g * 8;
  bf16x8 qf0 = *reinterpret_cast<const bf16x8*>(qp);
  bf16x8 qf1 = *reinterpret_cast<const bf16x8*>(qp + 32);

  // K staging via global_load_lds, pre-swizzled source:
  // LDS slot (row, c') = K[row][c' ^ (row&7)], row&7 == lane>>3
  const unsigned short* gK0 = QKV + (bS + wid * 16 + (lane >> 3)) * ld + HID + h * HD
                              + (((lane & 7) ^ (lane >> 3)) << 3);
  const unsigned short* gK1 = gK0 + 8 * ld;

  // V staging: reg -> swizzled transposed scalar writes (conflict-free)
  const int vr0 = tid >> 3, ch = tid & 7;
  const unsigned short* gV0 = QKV + (bS + vr0) * ld + 2 * HID + h * HD + (ch << 3);
  const unsigned short* gV1 = gV0 + 32 * ld;
  const int kr3 = vr0 & 7;
  const int kb0v = vr0 >> 3, kb1v = kb0v + 4;
  const int vtbase = ch * 512 + kr3;
  const int pre0 = (kb0v ^ ch) & 7, pre1 = (kb1v ^ ch) & 7;

  // log2-domain bias row (lane owns q = qbase + lr)
  const unsigned short* bD = D2 + (size_t)b * SEQ * SEQ
                             + (size_t)(qbase + lr) * SEQ + 4 * g;

  // prologue: stage tile 0 into buffer 0; preload bias for tile 0
  GLOAD16(gK0, &Ks[0][wid * 1024]);
  GLOAD16(gK1, &Ks[0][wid * 1024 + 512]);
  {
    u16x8 v0 = *reinterpret_cast<const u16x8*>(gV0);
    u16x8 v1 = *reinterpret_cast<const u16x8*>(gV1);
#pragma unroll
    for (int i = 0; i < 8; i++) {
      Vt[0][vtbase + i * 64 + ((pre0 ^ i) << 3)] = v0[i];
      Vt[0][vtbase + i * 64 + ((pre1 ^ i) << 3)] = v1[i];
    }
  }
  ushort4 bvc[4];
#pragma unroll
  for (int kc = 0; kc < 4; kc++)
    bvc[kc] = *reinterpret_cast<const ushort4*>(bD + kc * 16);
  __syncthreads();

  f32x4 acc[4] = {};
  f32x4 rsacc = {};
  const int kb0 = lr * 64 + ((g ^ (lr & 7)) << 3);
  const int plw = lr * 64;              // P row base
  const int plm = (lr & 7) << 3;        // P XOR mask (shorts)
  bf16x8 ones;
#pragma unroll
  for (int i = 0; i < 8; i++) ones[i] = 0x3F80;  // bf16 1.0

  for (int kt = 0; kt < 32; ++kt) {
    const int cb = kt & 1;
    const unsigned short* ks = &Ks[cb][0];
    const unsigned short* vt = &Vt[cb][0];
    u16x8 vv0 = {}, vv1 = {};
    ushort4 bvn[4];
    if (kt < 31) {  // prefetch next tile: K->LDS, V->regs, bias->regs
      GLOAD16(gK0 + (size_t)(kt + 1) * 64 * ld, &Ks[cb ^ 1][wid * 1024]);
      GLOAD16(gK1 + (size_t)(kt + 1) * 64 * ld, &Ks[cb ^ 1][wid * 1024 + 512]);
      vv0 = *reinterpret_cast<const u16x8*>(gV0 + (size_t)(kt + 1) * 64 * ld);
      vv1 = *reinterpret_cast<const u16x8*>(gV1 + (size_t)(kt + 1) * 64 * ld);
#pragma unroll
      for (int kc = 0; kc < 4; kc++)
        bvn[kc] = *reinterpret_cast<const ushort4*>(bD + (kt + 1) * 64 + kc * 16);
    }

    // S^T = K Q^T  (A = K frag, B = Q frag)
    f32x4 s[4];
    __builtin_amdgcn_s_setprio(1);
#pragma unroll
    for (int kc = 0; kc < 4; kc++) {
      bf16x8 kf0 = *reinterpret_cast<const bf16x8*>(ks + kc * 1024 + kb0);
      bf16x8 kf1 = *reinterpret_cast<const bf16x8*>(ks + kc * 1024 + (kb0 ^ 32));
      f32x4 z = {};
      z = __builtin_amdgcn_mfma_f32_16x16x32_bf16(kf0, qf0, z, 0, 0, 0);
      s[kc] = __builtin_amdgcn_mfma_f32_16x16x32_bf16(kf1, qf1, z, 0, 0, 0);
    }
    __builtin_amdgcn_s_setprio(0);

    // P = exp2(0.18*qk + bias) directly — no max tracking; pack by truncation
#pragma unroll
    for (int kc = 0; kc < 4; kc++) {
      float p0 = exp2f(fmaf(s[kc][0], C1, bf2f(bvc[kc].x)));
      float p1 = exp2f(fmaf(s[kc][1], C1, bf2f(bvc[kc].y)));
      float p2 = exp2f(fmaf(s[kc][2], C1, bf2f(bvc[kc].z)));
      float p3 = exp2f(fmaf(s[kc][3], C1, bf2f(bvc[kc].w)));
      uint2 w;
      w.x = __builtin_amdgcn_perm(__builtin_bit_cast(unsigned, p1),
                                  __builtin_bit_cast(unsigned, p0), 0x07060302u);
      w.y = __builtin_amdgcn_perm(__builtin_bit_cast(unsigned, p3),
                                  __builtin_bit_cast(unsigned, p2), 0x07060302u);
      *reinterpret_cast<uint2*>(&Pl[wid][plw + ((kc * 16 + 4 * g) ^ plm)]) = w;
    }

    // ctx += P V ; l += P . ones
    __builtin_amdgcn_s_setprio(1);
#pragma unroll
    for (int c2 = 0; c2 < 2; c2++) {
      bf16x8 pf = *reinterpret_cast<const bf16x8*>(
          &Pl[wid][plw + ((c2 * 32 + g * 8) ^ plm)]);
      rsacc = __builtin_amdgcn_mfma_f32_16x16x32_bf16(pf, ones, rsacc, 0, 0, 0);
#pragma unroll
      for (int df = 0; df < 4; df++) {
        int blk = ((4 * c2 + g) ^ (lr & 7) ^ ((df * 2 + (lr >> 3)) & 7)) & 7;
        bf16x8 vf = *reinterpret_cast<const bf16x8*>(vt + (df * 16 + lr) * 64 + (blk << 3));
        acc[df] = __builtin_amdgcn_mfma_f32_16x16x32_bf16(pf, vf, acc[df], 0, 0, 0);
      }
    }
    __builtin_amdgcn_s_setprio(0);

    // write next V tile (vmcnt drains here, after PV — true write-late)
    if (kt < 31) {
#pragma unroll
      for (int i = 0; i < 8; i++) {
        Vt[cb ^ 1][vtbase + i * 64 + ((pre0 ^ i) << 3)] = vv0[i];
        Vt[cb ^ 1][vtbase + i * 64 + ((pre1 ^ i) << 3)] = vv1[i];
      }
      bvc[0] = bvn[0]; bvc[1] = bvn[1]; bvc[2] = bvn[2]; bvc[3] = bvn[3];
    }
    __syncthreads();
  }
  // epilogue: normalize and store (stats already in acc row layout)
  float l0 = 1.0f / rsacc[0], l1 = 1.0f / rsacc[1];
  float l2 = 1.0f / rsacc[2], l3 = 1.0f / rsacc[3];
  unsigned short* op = ctxb + (bS + qbase + 4 * g) * HID + h * HD + lr;
#pragma unroll
  for (int df = 0; df < 4; df++) {
    op[0 * HID + df * 16] = f2bf(acc[df][0] * l0);
    op[1 * HID + df * 16] = f2bf(acc[df][1] * l1);
    op[2 * HID + df * 16] = f2bf(acc[df][2] * l2);
    op[3 * HID + df * 16] = f2bf(acc[df][3] * l3);
  }
}

extern "C" void kernel_launch(void* const* d_in, const int* in_sizes, int n_in,
                              void* d_out, int out_size, void* d_ws, size_t ws_size,
                              hipStream_t stream) {
  const float* x = (const float*)d_in[0];
  const unsigned char* mask = (const unsigned char*)d_in[1];
  const float* Wq = (const float*)d_in[2];
  const float* bq = (const float*)d_in[3];
  const float* Wk = (const float*)d_in[4];
  const float* bk = (const float*)d_in[5];
  const float* Wv = (const float*)d_in[6];
  const float* bv = (const float*)d_in[7];
  const float* Wo = (const float*)d_in[8];
  const float* bo = (const float*)d_in[9];
  float* out = (float*)d_out;

  char* ws = (char*)d_ws;
  const size_t MiB = 1024 * 1024;
  unsigned short* xb  = (unsigned short*)(ws + 0 * MiB);   // 8 MiB
  unsigned short* nxb = (unsigned short*)(ws + 8 * MiB);   // 8 MiB
  unsigned short* Wb  = (unsigned short*)(ws + 16 * MiB);  // 8 MiB
  unsigned short* QKV = (unsigned short*)(ws + 24 * MiB);  // 24 MiB [4096][3072]
  unsigned short* D2  = (unsigned short*)(ws + 48 * MiB);  // 16 MiB bf16 log2-bias
  unsigned short* ctx = (unsigned short*)(ws + 64 * MiB);  // 8 MiB

  convert_w_kernel<<<2048, 256, 0, stream>>>(Wq, Wk, Wv, Wo, Wb);
  rownorm_kernel<<<NB * SEQ, 256, 0, stream>>>(x, xb, nxb);
  // fused QKV projection
  gemm_nt<0><<<dim3(24, 32, 1), 256, 0, stream>>>(
      xb, 0, Wb, 0, QKV, 0, 3 * HID, NB * SEQ, 3 * HID, HID, bq, bk, bv, nullptr);
  // diversity bias (log2 domain, bf16): D' = -gamma*log2e*sim + mask*(-1e30)
  gemm_nt<1><<<dim3(16, 16, 2), 256, 0, stream>>>(
      nxb, (long)SEQ * HID, nxb, (long)SEQ * HID, D2, (long)SEQ * SEQ, SEQ,
      SEQ, SEQ, HID, nullptr, nullptr, nullptr, mask);
  // flash attention over all heads
  flash_kernel<<<dim3(NH, SEQ / 64, NB), 256, 0, stream>>>(QKV, D2, ctx);
  // output projection
  gemm_nt<2><<<dim3(8, 32, 1), 256, 0, stream>>>(
      ctx, 0, Wb + (size_t)3 * HID * HID, 0, out, 0, HID, NB * SEQ, HID, HID,
      bo, nullptr, nullptr, nullptr);
}

// Round 7
// 194.500 us; speedup vs baseline: 1.1063x; 1.1063x over previous
//
#include <hip/hip_runtime.h>

#define HID 1024
#define SEQ 2048
#define NB 2
#define NH 16
#define HD 64

// 0.125 * log2(e)  (1/sqrt(64) folded into log2 domain)
#define C1 0.1803368801111204f
// gamma * log2(e)
#define C2 0.7213475204444817f

typedef __attribute__((ext_vector_type(8))) short bf16x8;
typedef __attribute__((ext_vector_type(8))) unsigned short u16x8;
typedef __attribute__((ext_vector_type(4))) float f32x4;

__device__ __forceinline__ unsigned short f2bf(float f) {
  unsigned u = __builtin_bit_cast(unsigned, f);
  u += 0x7fffu + ((u >> 16) & 1u);
  return (unsigned short)(u >> 16);
}
__device__ __forceinline__ float bf2f(unsigned short u) {
  return __builtin_bit_cast(float, ((unsigned)u) << 16);
}

#define GLOAD16(gsrc, ldst)                                                     \
  __builtin_amdgcn_global_load_lds(                                             \
      (const __attribute__((address_space(1))) void*)(gsrc),                    \
      (__attribute__((address_space(3))) void*)(ldst), 16, 0, 0)

// ---- convert the 4 weight matrices f32 -> bf16 into one contiguous buffer ----
__global__ __launch_bounds__(256) void convert_w_kernel(
    const float* __restrict__ Wq, const float* __restrict__ Wk,
    const float* __restrict__ Wv, const float* __restrict__ Wo,
    unsigned short* __restrict__ Wb) {
  int i = blockIdx.x * 256 + threadIdx.x;
  const int per = (HID * HID) / 8;
  int m = i / per;
  const float* sp = (m == 0) ? Wq : (m == 1) ? Wk : (m == 2) ? Wv : Wo;
  int j = (i - m * per) * 8;
  const float4* p = reinterpret_cast<const float4*>(sp + j);
  float4 a = p[0], b = p[1];
  u16x8 o;
  o[0] = f2bf(a.x); o[1] = f2bf(a.y); o[2] = f2bf(a.z); o[3] = f2bf(a.w);
  o[4] = f2bf(b.x); o[5] = f2bf(b.y); o[6] = f2bf(b.z); o[7] = f2bf(b.w);
  *reinterpret_cast<u16x8*>(Wb + (size_t)i * 8) = o;
}

// ---- per-row L2 norm of x; emit x (bf16) and normalized x (bf16) ----
__global__ __launch_bounds__(256) void rownorm_kernel(
    const float* __restrict__ x, unsigned short* __restrict__ xb,
    unsigned short* __restrict__ nxb) {
  int row = blockIdx.x, tid = threadIdx.x;
  const float4 v = reinterpret_cast<const float4*>(x + (size_t)row * HID)[tid];
  float ss = v.x * v.x + v.y * v.y + v.z * v.z + v.w * v.w;
#pragma unroll
  for (int off = 32; off; off >>= 1) ss += __shfl_xor(ss, off, 64);
  __shared__ float wsum[4];
  if ((tid & 63) == 0) wsum[tid >> 6] = ss;
  __syncthreads();
  float tot = wsum[0] + wsum[1] + wsum[2] + wsum[3];
  float inv = 1.0f / fmaxf(sqrtf(tot), 1e-12f);
  ushort4 a, b;
  a.x = f2bf(v.x); a.y = f2bf(v.y); a.z = f2bf(v.z); a.w = f2bf(v.w);
  b.x = f2bf(v.x * inv); b.y = f2bf(v.y * inv);
  b.z = f2bf(v.z * inv); b.w = f2bf(v.w * inv);
  reinterpret_cast<ushort4*>(xb  + (size_t)row * HID)[tid] = a;
  reinterpret_cast<ushort4*>(nxb + (size_t)row * HID)[tid] = b;
}

// ---- generic NT bf16 GEMM: C = A[M,K] * B[N,K]^T, f32 accum ----
// Staging via global_load_lds width=16 into unpadded [128][32] tiles.
template <int MODE>
__global__ __launch_bounds__(256) void gemm_nt(
    const unsigned short* __restrict__ A, long strideA,
    const unsigned short* __restrict__ B, long strideB,
    void* __restrict__ Cv, long strideC, int ldc,
    int M, int N, int K,
    const float* __restrict__ b0, const float* __restrict__ b1,
    const float* __restrict__ b2, const unsigned char* __restrict__ mask) {
  __shared__ __align__(16) unsigned short As[128 * 32];
  __shared__ __align__(16) unsigned short Bs[128 * 32];
  int tid = threadIdx.x, lane = tid & 63, wid = tid >> 6;
  int g = lane >> 4, lr = lane & 15;
  int wr = wid >> 1, wc = wid & 1;
  int m0 = blockIdx.y * 128, n0 = blockIdx.x * 128;
  const unsigned short* Ab = A + (size_t)blockIdx.z * strideA
      + (size_t)(m0 + wid * 32 + (lane >> 2)) * K + (lane & 3) * 8;
  const unsigned short* Bb = B + (size_t)blockIdx.z * strideB
      + (size_t)(n0 + wid * 32 + (lane >> 2)) * K + (lane & 3) * 8;
  unsigned short* la = As + wid * 1024;
  unsigned short* lb = Bs + wid * 1024;
  f32x4 acc[4][4] = {};
  for (int k0 = 0; k0 < K; k0 += 32) {
    GLOAD16(Ab + k0, la);
    GLOAD16(Ab + 16 * K + k0, la + 512);
    GLOAD16(Bb + k0, lb);
    GLOAD16(Bb + 16 * K + k0, lb + 512);
    __syncthreads();
    bf16x8 af[4], bfr[4];
#pragma unroll
    for (int i = 0; i < 4; i++) {
      af[i]  = *reinterpret_cast<const bf16x8*>(&As[(wr * 64 + i * 16 + lr) * 32 + g * 8]);
      bfr[i] = *reinterpret_cast<const bf16x8*>(&Bs[(wc * 64 + i * 16 + lr) * 32 + g * 8]);
    }
#pragma unroll
    for (int i = 0; i < 4; i++)
#pragma unroll
      for (int j = 0; j < 4; j++)
        acc[i][j] = __builtin_amdgcn_mfma_f32_16x16x32_bf16(af[i], bfr[j], acc[i][j], 0, 0, 0);
    __syncthreads();
  }
#pragma unroll
  for (int i = 0; i < 4; i++)
#pragma unroll
    for (int j = 0; j < 4; j++) {
      int col = n0 + wc * 64 + j * 16 + lr;
#pragma unroll
      for (int r = 0; r < 4; r++) {
        int row = m0 + wr * 64 + i * 16 + 4 * g + r;
        float v = acc[i][j][r];
        if (MODE == 0) {
          const float* bp = (col < 1024) ? b0 : (col < 2048 ? b1 : b2);
          v += bp[col & 1023];
          ((unsigned short*)Cv)[(size_t)blockIdx.z * strideC + (size_t)row * ldc + col] = f2bf(v);
        } else if (MODE == 1) {
          float t = -C2 * v + (mask[(size_t)row * N + col] ? -1e30f : 0.0f);
          ((unsigned short*)Cv)[(size_t)blockIdx.z * strideC + (size_t)row * ldc + col] = f2bf(t);
        } else {
          v += b0[col];
          ((float*)Cv)[(size_t)blockIdx.z * strideC + (size_t)row * ldc + col] = v;
        }
      }
    }
}

// ---- flash attention v6: in-register P via kappa-permuted K staging ----
// K LDS position p holds key kappa(p) = 32*(p>>5&1)? ... kappa(16kc+4g+r) =
// 32(kc>>1)+8g+4(kc&1)+r, so lane (g,lr)'s post-softmax P values are exactly
// its PV A-fragment slots (j = 4(kc&1)+r, frag c2 = kc>>1). P never touches
// LDS. V staging identity (B slot (g,j) = key 32c2+8g+j). No-max softmax.
__global__ __launch_bounds__(256, 4) void flash_kernel(
    const unsigned short* __restrict__ QKV,  // [4096][3072] bf16 (Q|K|V)
    const unsigned short* __restrict__ D2,   // [2][2048][2048] bf16 log2-bias
    unsigned short* __restrict__ ctxb) {     // [4096][1024] bf16
  int h = blockIdx.x, qt = blockIdx.y, b = blockIdx.z;
  int tid = threadIdx.x, wid = tid >> 6, lane = tid & 63;
  int g = lane >> 4, lr = lane & 15;
  __shared__ __align__(16) unsigned short Ks[2][64 * 64];  // 16 KiB
  __shared__ __align__(16) unsigned short Vt[2][64 * 64];  // 16 KiB
  const size_t ld = 3 * HID;
  const size_t bS = (size_t)b * SEQ;
  const int qbase = qt * 64 + wid * 16;

  // Q fragment (B operand): rows qbase+lr; lane group g holds d=8g+j (+32)
  const unsigned short* qp = QKV + (bS + qbase + lr) * ld + h * HD + g * 8;
  bf16x8 qf0 = *reinterpret_cast<const bf16x8*>(qp);
  bf16x8 qf1 = *reinterpret_cast<const bf16x8*>(qp + 32);

  // K staging: LDS position row p = wid*16 + (lane>>3) (+8 for gK1) holds
  // key kappa(p); chunk swizzle c' = (lane&7) ^ (p&7) unchanged (p&7 = lane>>3).
  const int p0 = wid * 16 + (lane >> 3);
  const int key0 = ((p0 >> 5) & 1) * 32 + (((p0 >> 2) & 3) << 3)
                 + ((p0 >> 4) & 1) * 4 + (p0 & 3);  // kappa(p0); kappa(p0+8)=key0+16
  const unsigned short* gK0 = QKV + (bS + key0) * ld + HID + h * HD
                              + (((lane & 7) ^ (lane >> 3)) << 3);
  const unsigned short* gK1 = gK0 + 16 * ld;  // kappa(p0+8) = key0 + 16

  // V staging: identity column order, reg -> swizzled transposed scalar writes
  const int vr0 = tid >> 3, ch = tid & 7;
  const unsigned short* gV0 = QKV + (bS + vr0) * ld + 2 * HID + h * HD + (ch << 3);
  const unsigned short* gV1 = gV0 + 32 * ld;
  const int kr3 = vr0 & 7;
  const int kb0v = vr0 >> 3, kb1v = kb0v + 4;
  const int vtbase = ch * 512 + kr3;
  const int pre0 = (kb0v ^ ch) & 7, pre1 = (kb1v ^ ch) & 7;

  // log2-domain bias row (lane owns q = qbase + lr); kappa key offsets per kc
  const unsigned short* bD = D2 + (size_t)b * SEQ * SEQ
                             + (size_t)(qbase + lr) * SEQ + 8 * g;
  // kc offsets: 32*(kc>>1) + 4*(kc&1) = {0, 4, 32, 36}

  // prologue: stage tile 0 into buffer 0; preload bias for tile 0
  GLOAD16(gK0, &Ks[0][wid * 1024]);
  GLOAD16(gK1, &Ks[0][wid * 1024 + 512]);
  {
    u16x8 v0 = *reinterpret_cast<const u16x8*>(gV0);
    u16x8 v1 = *reinterpret_cast<const u16x8*>(gV1);
#pragma unroll
    for (int i = 0; i < 8; i++) {
      Vt[0][vtbase + i * 64 + ((pre0 ^ i) << 3)] = v0[i];
      Vt[0][vtbase + i * 64 + ((pre1 ^ i) << 3)] = v1[i];
    }
  }
  ushort4 bvc[4];
  bvc[0] = *reinterpret_cast<const ushort4*>(bD + 0);
  bvc[1] = *reinterpret_cast<const ushort4*>(bD + 4);
  bvc[2] = *reinterpret_cast<const ushort4*>(bD + 32);
  bvc[3] = *reinterpret_cast<const ushort4*>(bD + 36);
  __syncthreads();

  f32x4 acc[4] = {};
  f32x4 rsacc = {};
  const int kb0 = lr * 64 + ((g ^ (lr & 7)) << 3);
  bf16x8 ones;
#pragma unroll
  for (int i = 0; i < 8; i++) ones[i] = 0x3F80;  // bf16 1.0

  for (int kt = 0; kt < 32; ++kt) {
    const int cb = kt & 1;
    const unsigned short* ks = &Ks[cb][0];
    const unsigned short* vt = &Vt[cb][0];
    u16x8 vv0 = {}, vv1 = {};
    ushort4 bvn[4];
    if (kt < 31) {  // prefetch next tile: K->LDS, V->regs, bias->regs
      GLOAD16(gK0 + (size_t)(kt + 1) * 64 * ld, &Ks[cb ^ 1][wid * 1024]);
      GLOAD16(gK1 + (size_t)(kt + 1) * 64 * ld, &Ks[cb ^ 1][wid * 1024 + 512]);
      vv0 = *reinterpret_cast<const u16x8*>(gV0 + (size_t)(kt + 1) * 64 * ld);
      vv1 = *reinterpret_cast<const u16x8*>(gV1 + (size_t)(kt + 1) * 64 * ld);
      const unsigned short* bn = bD + (kt + 1) * 64;
      bvn[0] = *reinterpret_cast<const ushort4*>(bn + 0);
      bvn[1] = *reinterpret_cast<const ushort4*>(bn + 4);
      bvn[2] = *reinterpret_cast<const ushort4*>(bn + 32);
      bvn[3] = *reinterpret_cast<const ushort4*>(bn + 36);
    }

    // S^T = K Q^T  (A = K frag from kappa-permuted LDS, B = Q frag)
    f32x4 s[4];
    __builtin_amdgcn_s_setprio(1);
#pragma unroll
    for (int kc = 0; kc < 4; kc++) {
      bf16x8 kf0 = *reinterpret_cast<const bf16x8*>(ks + kc * 1024 + kb0);
      bf16x8 kf1 = *reinterpret_cast<const bf16x8*>(ks + kc * 1024 + (kb0 ^ 32));
      f32x4 z = {};
      z = __builtin_amdgcn_mfma_f32_16x16x32_bf16(kf0, qf0, z, 0, 0, 0);
      s[kc] = __builtin_amdgcn_mfma_f32_16x16x32_bf16(kf1, qf1, z, 0, 0, 0);
    }
    __builtin_amdgcn_s_setprio(0);

    // P = exp2(0.18*qk + bias) directly; pack in-register into PV A-frags
    bf16x8 pa[2];
#pragma unroll
    for (int c2 = 0; c2 < 2; c2++) {
      float p0f = exp2f(fmaf(s[2 * c2][0], C1, bf2f(bvc[2 * c2].x)));
      float p1f = exp2f(fmaf(s[2 * c2][1], C1, bf2f(bvc[2 * c2].y)));
      float p2f = exp2f(fmaf(s[2 * c2][2], C1, bf2f(bvc[2 * c2].z)));
      float p3f = exp2f(fmaf(s[2 * c2][3], C1, bf2f(bvc[2 * c2].w)));
      float p4f = exp2f(fmaf(s[2 * c2 + 1][0], C1, bf2f(bvc[2 * c2 + 1].x)));
      float p5f = exp2f(fmaf(s[2 * c2 + 1][1], C1, bf2f(bvc[2 * c2 + 1].y)));
      float p6f = exp2f(fmaf(s[2 * c2 + 1][2], C1, bf2f(bvc[2 * c2 + 1].z)));
      float p7f = exp2f(fmaf(s[2 * c2 + 1][3], C1, bf2f(bvc[2 * c2 + 1].w)));
      uint4 W;
      W.x = __builtin_amdgcn_perm(__builtin_bit_cast(unsigned, p1f),
                                  __builtin_bit_cast(unsigned, p0f), 0x07060302u);
      W.y = __builtin_amdgcn_perm(__builtin_bit_cast(unsigned, p3f),
                                  __builtin_bit_cast(unsigned, p2f), 0x07060302u);
      W.z = __builtin_amdgcn_perm(__builtin_bit_cast(unsigned, p5f),
                                  __builtin_bit_cast(unsigned, p4f), 0x07060302u);
      W.w = __builtin_amdgcn_perm(__builtin_bit_cast(unsigned, p7f),
                                  __builtin_bit_cast(unsigned, p6f), 0x07060302u);
      pa[c2] = __builtin_bit_cast(bf16x8, W);
    }

    // ctx += P V ; l += P . ones   (P straight from registers)
    __builtin_amdgcn_s_setprio(1);
#pragma unroll
    for (int c2 = 0; c2 < 2; c2++) {
      rsacc = __builtin_amdgcn_mfma_f32_16x16x32_bf16(pa[c2], ones, rsacc, 0, 0, 0);
#pragma unroll
      for (int df = 0; df < 4; df++) {
        int blk = ((4 * c2 + g) ^ (lr & 7) ^ ((df * 2 + (lr >> 3)) & 7)) & 7;
        bf16x8 vf = *reinterpret_cast<const bf16x8*>(vt + (df * 16 + lr) * 64 + (blk << 3));
        acc[df] = __builtin_amdgcn_mfma_f32_16x16x32_bf16(pa[c2], vf, acc[df], 0, 0, 0);
      }
    }
    __builtin_amdgcn_s_setprio(0);

    // write next V tile (vmcnt drains here, after PV — write-late)
    if (kt < 31) {
#pragma unroll
      for (int i = 0; i < 8; i++) {
        Vt[cb ^ 1][vtbase + i * 64 + ((pre0 ^ i) << 3)] = vv0[i];
        Vt[cb ^ 1][vtbase + i * 64 + ((pre1 ^ i) << 3)] = vv1[i];
      }
      bvc[0] = bvn[0]; bvc[1] = bvn[1]; bvc[2] = bvn[2]; bvc[3] = bvn[3];
    }
    __syncthreads();
  }
  // epilogue: normalize and store (stats already in acc row layout)
  float l0 = 1.0f / rsacc[0], l1 = 1.0f / rsacc[1];
  float l2 = 1.0f / rsacc[2], l3 = 1.0f / rsacc[3];
  unsigned short* op = ctxb + (bS + qbase + 4 * g) * HID + h * HD + lr;
#pragma unroll
  for (int df = 0; df < 4; df++) {
    op[0 * HID + df * 16] = f2bf(acc[df][0] * l0);
    op[1 * HID + df * 16] = f2bf(acc[df][1] * l1);
    op[2 * HID + df * 16] = f2bf(acc[df][2] * l2);
    op[3 * HID + df * 16] = f2bf(acc[df][3] * l3);
  }
}

extern "C" void kernel_launch(void* const* d_in, const int* in_sizes, int n_in,
                              void* d_out, int out_size, void* d_ws, size_t ws_size,
                              hipStream_t stream) {
  const float* x = (const float*)d_in[0];
  const unsigned char* mask = (const unsigned char*)d_in[1];
  const float* Wq = (const float*)d_in[2];
  const float* bq = (const float*)d_in[3];
  const float* Wk = (const float*)d_in[4];
  const float* bk = (const float*)d_in[5];
  const float* Wv = (const float*)d_in[6];
  const float* bv = (const float*)d_in[7];
  const float* Wo = (const float*)d_in[8];
  const float* bo = (const float*)d_in[9];
  float* out = (float*)d_out;

  char* ws = (char*)d_ws;
  const size_t MiB = 1024 * 1024;
  unsigned short* xb  = (unsigned short*)(ws + 0 * MiB);   // 8 MiB
  unsigned short* nxb = (unsigned short*)(ws + 8 * MiB);   // 8 MiB
  unsigned short* Wb  = (unsigned short*)(ws + 16 * MiB);  // 8 MiB
  unsigned short* QKV = (unsigned short*)(ws + 24 * MiB);  // 24 MiB [4096][3072]
  unsigned short* D2  = (unsigned short*)(ws + 48 * MiB);  // 16 MiB bf16 log2-bias
  unsigned short* ctx = (unsigned short*)(ws + 64 * MiB);  // 8 MiB

  convert_w_kernel<<<2048, 256, 0, stream>>>(Wq, Wk, Wv, Wo, Wb);
  rownorm_kernel<<<NB * SEQ, 256, 0, stream>>>(x, xb, nxb);
  // fused QKV projection
  gemm_nt<0><<<dim3(24, 32, 1), 256, 0, stream>>>(
      xb, 0, Wb, 0, QKV, 0, 3 * HID, NB * SEQ, 3 * HID, HID, bq, bk, bv, nullptr);
  // diversity bias (log2 domain, bf16): D' = -gamma*log2e*sim + mask*(-1e30)
  gemm_nt<1><<<dim3(16, 16, 2), 256, 0, stream>>>(
      nxb, (long)SEQ * HID, nxb, (long)SEQ * HID, D2, (long)SEQ * SEQ, SEQ,
      SEQ, SEQ, HID, nullptr, nullptr, nullptr, mask);
  // flash attention over all heads
  flash_kernel<<<dim3(NH, SEQ / 64, NB), 256, 0, stream>>>(QKV, D2, ctx);
  // output projection
  gemm_nt<2><<<dim3(8, 32, 1), 256, 0, stream>>>(
      ctx, 0, Wb + (size_t)3 * HID * HID, 0, out, 0, HID, NB * SEQ, HID, HID,
      bo, nullptr, nullptr, nullptr);
}